// Round 9
// baseline (312.601 us; speedup 1.0000x reference)
//
#include <hip/hip_runtime.h>
#include <hip/hip_bf16.h>
#include <stdint.h>
#include <math.h>

typedef short short8 __attribute__((ext_vector_type(8)));
typedef short short4v __attribute__((ext_vector_type(4)));
typedef float float4v __attribute__((ext_vector_type(4)));
typedef float float2v __attribute__((ext_vector_type(2)));

static __device__ __forceinline__ float bf2f(uint16_t u) {
    union { uint32_t i; float f; } x; x.i = ((uint32_t)u) << 16; return x.f;
}
static __device__ __forceinline__ uint16_t f2bf(float f) {
    union { float f; uint32_t i; } x; x.f = f;
    uint32_t u = x.i;
    u += 0x7FFFu + ((u >> 16) & 1u);   // RNE
    return (uint16_t)(u >> 16);
}
// hardware f32->bf16 via compiler (RNE, bit-identical to f2bf for finite
// values; lowers to v_cvt_pk_bf16_f32 pairs on gfx950)
static __device__ __forceinline__ uint16_t f2bf_hw(float f) {
    __hip_bfloat16 h = __float2bfloat16(f);
    uint16_t u; __builtin_memcpy(&u, &h, 2); return u;
}
static __device__ __forceinline__ uint16_t f2bf_sane(float f) {
    uint16_t u = f2bf(f);
    if ((u & 0x7F80u) == 0x7F80u) u = 0;
    return u;
}
static __device__ __forceinline__ float san_f32(float f) {
    union { float f; uint32_t i; } x; x.f = f;
    if (((x.i >> 23) & 0xFFu) == 0xFFu) return 0.f;
    return x.f;
}
static __device__ __forceinline__ void gll16(const void* g, void* l) {
    __builtin_amdgcn_global_load_lds((const __attribute__((address_space(1))) void*)g,
                                     (__attribute__((address_space(3))) void*)l,
                                     16, 0, 0);
}
static __device__ __forceinline__ short8 load8(const void* p, size_t off, int fp32) {
    if (!fp32) return *(const short8*)((const uint16_t*)p + off);
    const float* f = (const float*)p + off;
    const float4v a = *(const float4v*)f;
    const float4v b = *(const float4v*)(f + 4);
    short8 r;
    r[0] = (short)f2bf(a[0]); r[1] = (short)f2bf(a[1]);
    r[2] = (short)f2bf(a[2]); r[3] = (short)f2bf(a[3]);
    r[4] = (short)f2bf(b[0]); r[5] = (short)f2bf(b[1]);
    r[6] = (short)f2bf(b[2]); r[7] = (short)f2bf(b[3]);
    return r;
}

// raw 2^x (hardware v_exp_f32). Q is pre-scaled by log2(e)/sqrt(DK).
static __device__ __forceinline__ float fexp2(float x) {
#if __has_builtin(__builtin_amdgcn_exp2f)
    return __builtin_amdgcn_exp2f(x);
#else
    float r; asm("v_exp_f32 %0, %1\ns_nop 0" : "=v"(r) : "v"(x)); return r;
#endif
}

// masked exp2: bit r of nib selects s, else -inf (exp2(-inf)=+0).
static __device__ __forceinline__ float maskexp2(float s, uint32_t nib, int r) {
    union { float f; uint32_t u; } x; x.f = s;
    const uint32_t keep = (uint32_t)(((int32_t)(nib << (31 - r))) >> 31);
    x.u = (x.u & keep) | (~keep & 0xFF800000u);
    return fexp2(x.f);
}

// 16x16x16 bf16 MFMA: builtin if present, else raw asm (hazard nops at use site)
static __device__ __forceinline__ float4v mfma16_bf16(short4v a, short4v b, float4v c) {
#if __has_builtin(__builtin_amdgcn_mfma_f32_16x16x16bf16_1k)
    return __builtin_amdgcn_mfma_f32_16x16x16bf16_1k(a, b, c, 0, 0, 0);
#else
    float4v d = c;
    asm volatile("v_mfma_f32_16x16x16_bf16 %0, %1, %2, %0"
                 : "+v"(d) : "v"(a), "v"(b));
    return d;
#endif
}

// ---------------------------------------------------------------------------
// pack: blocks 0-1023: mask bitpack int32[4096][2048] -> uint64[4096][32].
// block 1024: dtype probe -> *flag. blocks 1025-1536: weight fp32->bf16
// convert (mode decided locally — same probe data, deterministic, no race
// on flag within the dispatch). block 1537: bias convert.
// Input (qx/kx/vx) conversion is FUSED INTO qkv's A-staging (r9): deletes
// the 48MB-read + 24MB-write convert pass entirely.
// ---------------------------------------------------------------------------
__global__ __launch_bounds__(256) void pack_kernel(
    const int* __restrict__ mask, uint64_t* __restrict__ mask64,
    const uint16_t* __restrict__ qx, int* __restrict__ flag,
    const void* wq, const void* wk, const void* wv, const void* wo,
    const void* bq, const void* bk, const void* bv, const void* bo,
    uint16_t* __restrict__ cW, uint16_t* __restrict__ cB)
{
    const int bx = blockIdx.x;
    const int tid = threadIdx.x;
    if (bx < 1024) {
        const int wave = tid >> 6, lane = tid & 63;
        const int row = bx * 4 + wave;
        const int* src = mask + (size_t)row * 2048;
#pragma unroll 4
        for (int j = 0; j < 32; ++j) {
            const int m = src[j * 64 + lane];
            const uint64_t bal = __ballot(m != 0);
            if (lane == 0) mask64[(size_t)row * 32 + j] = bal;
        }
        return;
    }
    // local dtype probe (blocks >= 1024): scan first 16K halfwords of qx
    __shared__ int s;
    if (tid == 0) s = 0;
    __syncthreads();
    int bad = 0;
#pragma unroll 8
    for (int i = 0; i < 64; ++i) {
        const uint16_t u = qx[tid * 64 + i];
        bad |= ((u & 0x7F80u) == 0x7F80u) ? 1 : 0;
    }
    if (bad) atomicOr(&s, 1);
    __syncthreads();
    const int mode = s;
    if (bx == 1024) {
        if (tid == 0) *flag = mode;
        return;
    }
    if (!mode) return;
    if (bx < 1537) {
        const int idx8 = (bx - 1025) * 256 + tid;    // [0, 131072)
#pragma unroll
        for (int t = 0; t < 4; ++t) {
            const void* src = (t == 0) ? wq : (t == 1) ? wk : (t == 2) ? wv : wo;
            *(short8*)(cW + (size_t)t * 1048576 + (size_t)idx8 * 8) =
                load8(src, (size_t)idx8 * 8, 1);
        }
    } else {
        if (tid < 128) {
#pragma unroll
            for (int t = 0; t < 4; ++t) {
                const void* src = (t == 0) ? bq : (t == 1) ? bk : (t == 2) ? bv : bo;
                *(short8*)(cB + t * 1024 + tid * 8) = load8(src, (size_t)tid * 8, 1);
            }
        }
    }
}

// ---------------------------------------------------------------------------
// m97-style GEMM: C = A @ W^T + bias, all-bf16 compute, fp32 acc.
// afp32=1: A is fp32 in global; staged via reg (load float8 -> hw-RNE cvt ->
// ds_write_b128 to the same LDS layout gll16 would produce). W always bf16
// via gll16. (bx, by) passed in for XCD remap (T1).
// ---------------------------------------------------------------------------
template <int MI, int NI>
static __device__ __forceinline__ void gemm_tile(
    const void* __restrict__ A, int afp32,
    const uint16_t* __restrict__ W,
    const uint16_t* __restrict__ bias, void* __restrict__ C,
    int c_fp32, float out_scale, int bx, int by)
{
    constexpr int TM = MI * 32, TN = NI * 32;
    __shared__ __align__(16) uint16_t sA[TM * 32];
    __shared__ __align__(16) uint16_t sB[TN * 32];

    const int tid  = threadIdx.x;
    const int wave = tid >> 6;
    const int lane = tid & 63;
    const int quad = lane >> 4;
    const int l15  = lane & 15;
    const int m0 = by * TM;
    const int n0 = bx * TN;
    const int wm = (wave >> 1) * (MI * 16);
    const int wn = (wave & 1) * (NI * 16);
    const int r16 = lane >> 2;
    const int ch  = lane & 3;

    float4v acc[MI][NI] = {};

    for (int k0 = 0; k0 < 1024; k0 += 32) {
        __syncthreads();
        if (afp32) {
            const float* Af = (const float*)A;
#pragma unroll
            for (int g = wave; g < TM / 16; g += 4) {
                const float* p = Af + (size_t)(m0 + g * 16 + r16) * 1024 + k0 + ch * 8;
                const float4v a = *(const float4v*)p;
                const float4v b2 = *(const float4v*)(p + 4);
                short8 r;
                r[0] = (short)f2bf_hw(a[0]);  r[1] = (short)f2bf_hw(a[1]);
                r[2] = (short)f2bf_hw(a[2]);  r[3] = (short)f2bf_hw(a[3]);
                r[4] = (short)f2bf_hw(b2[0]); r[5] = (short)f2bf_hw(b2[1]);
                r[6] = (short)f2bf_hw(b2[2]); r[7] = (short)f2bf_hw(b2[3]);
                *(short8*)((char*)sA + (size_t)g * 1024 + (size_t)lane * 16) = r;
            }
        } else {
            const uint16_t* Ah = (const uint16_t*)A;
#pragma unroll
            for (int g = wave; g < TM / 16; g += 4)
                gll16(Ah + (size_t)(m0 + g * 16 + r16) * 1024 + k0 + ch * 8,
                      (char*)sA + (size_t)g * 1024);
        }
#pragma unroll
        for (int g = wave; g < TN / 16; g += 4)
            gll16(W + (size_t)(n0 + g * 16 + r16) * 1024 + k0 + ch * 8,
                  (char*)sB + (size_t)g * 1024);
        asm volatile("s_waitcnt vmcnt(0)" ::: "memory");
        __syncthreads();

        short8 af[MI], bfr[NI];
#pragma unroll
        for (int i = 0; i < MI; ++i)
            af[i] = *(const short8*)&sA[(wm + i * 16 + l15) * 32 + quad * 8];
#pragma unroll
        for (int j = 0; j < NI; ++j)
            bfr[j] = *(const short8*)&sB[(wn + j * 16 + l15) * 32 + quad * 8];
#pragma unroll
        for (int mi = 0; mi < MI; ++mi)
#pragma unroll
            for (int ni = 0; ni < NI; ++ni)
                acc[mi][ni] = __builtin_amdgcn_mfma_f32_16x16x32_bf16(
                    af[mi], bfr[ni], acc[mi][ni], 0, 0, 0);
    }

#pragma unroll
    for (int ni = 0; ni < NI; ++ni) {
        const int n = n0 + wn + ni * 16 + l15;
        const float bv = bf2f(bias[n]);
#pragma unroll
        for (int mi = 0; mi < MI; ++mi) {
            const int mbase = m0 + wm + mi * 16 + quad * 4;
#pragma unroll
            for (int r = 0; r < 4; ++r) {
                const float v = (acc[mi][ni][r] + bv) * out_scale;
                const size_t idx = (size_t)(mbase + r) * 1024 + n;
                if (c_fp32) ((float*)C)[idx] = san_f32(v);
                else        ((uint16_t*)C)[idx] = f2bf_sane(v);
            }
        }
    }
}

// XCD-affinity remap (T1): all 8 N-tile blocks of one (z, M-panel) share
// wgid%8 -> same XCD -> A-panel read once per XCD.
__global__ __launch_bounds__(256) void qkv_kernel(
    const void* qxr, const void* kxr, const void* vxr,
    const uint16_t* rwq, const uint16_t* rwk, const uint16_t* rwv,
    const uint16_t* rbq, const uint16_t* rbk, const uint16_t* rbv,
    const uint16_t* cW, const uint16_t* cB,
    uint16_t* Q, uint16_t* K, uint16_t* V, const int* flag)
{
    const int mode = *flag;
    const int wgid = blockIdx.x + (blockIdx.y << 3) + (blockIdx.z << 8);
    const int xcd = wgid & 7;
    const int s   = wgid >> 3;             // [0,96)
    const int panel = xcd * 12 + (s >> 3); // [0,96)
    const int bx = s & 7;
    const int z  = panel >> 5;             // [0,3)
    const int by = panel & 31;

    const void* A = (z == 0) ? qxr : (z == 1) ? kxr : vxr;  // fp32 if mode
    const uint16_t* W = mode ? cW + (size_t)z * 1048576
                             : ((z == 0) ? rwq : (z == 1) ? rwk : rwv);
    const uint16_t* b = mode ? cB + z * 1024
                             : ((z == 0) ? rbq : (z == 1) ? rbk : rbv);
    uint16_t* C = (z == 0) ? Q : (z == 1) ? K : V;
    // fold log2(e)/sqrt(DK) into Q so attention uses raw v_exp_f32 (2^x)
    const float sc = (z == 0) ? 0.18033688f : 1.0f;
    gemm_tile<4, 4>(A, mode, W, b, C, 0, sc, bx, by);
}

__global__ __launch_bounds__(256) void out_kernel(
    const uint16_t* Z, const uint16_t* rwo, const uint16_t* rbo,
    const uint16_t* cW, const uint16_t* cB, void* out, const int* flag)
{
    const int mode = *flag;
    const uint16_t* W = mode ? cW + 3 * 1048576 : rwo;
    const uint16_t* b = mode ? cB + 3 * 1024 : rbo;
    const int wgid = blockIdx.x + (blockIdx.y << 3);
    const int xcd = wgid & 7;
    const int s   = wgid >> 3;            // [0,64)
    const int by  = xcd * 8 + (s >> 3);   // [0,64)
    const int bx  = s & 7;
    gemm_tile<2, 4>(Z, 0, W, b, out, mode, 1.0f, bx, by);
}

// ---------------------------------------------------------------------------
// V transpose: V[B*L][H*64] -> Vt[B][H][64][L]  (coalesced both sides)
// ---------------------------------------------------------------------------
__global__ __launch_bounds__(256) void vtrans_kernel(
    const uint16_t* __restrict__ Vp, uint16_t* __restrict__ Vt)
{
    __shared__ __align__(16) uint16_t t[64][72];
    const int tid = threadIdx.x;
    const int lt = blockIdx.x, h = blockIdx.y, b = blockIdx.z;
#pragma unroll
    for (int p = 0; p < 2; ++p) {
        const int r = p * 32 + (tid >> 3);
        const int c = (tid & 7) * 8;
        *(short8*)&t[r][c] =
            *(const short8*)(Vp + (size_t)(b * 2048 + lt * 64 + r) * 1024 + h * 64 + c);
    }
    __syncthreads();
#pragma unroll
    for (int p = 0; p < 2; ++p) {
        const int d = p * 32 + (tid >> 3);
        const int c = (tid & 7) * 8;
        short8 v;
#pragma unroll
        for (int j = 0; j < 8; ++j) v[j] = (short)t[c + j][d];
        *(short8*)(Vt + (size_t)((b * 16 + h) * 64 + d) * 2048 + lt * 64 + c) = v;
    }
}

// ---------------------------------------------------------------------------
// Flash attention v12 (unchanged from r8): kt-split x3, T14 reg prefetch,
// setprio, exp2-prescale, bfi mask, f2bf_hw packs.
// ---------------------------------------------------------------------------
#define VS 72

__global__ __launch_bounds__(256, 4) void attn_kernel(
    const uint16_t* __restrict__ Q, const uint16_t* __restrict__ Kp,
    const uint16_t* __restrict__ Vt, const uint64_t* __restrict__ mask64,
    uint16_t* __restrict__ Oa, uint16_t* __restrict__ Ob,
    uint16_t* __restrict__ Oc, float* __restrict__ lpart)
{
    __shared__ __align__(16) uint16_t sK[64 * VS];
    __shared__ __align__(16) uint16_t sV[64 * VS];

    const int tid = threadIdx.x;
    const int wave = tid >> 6, lane = tid & 63;
    const int quad = lane >> 4, l15 = lane & 15;
    const int qt = blockIdx.x, h = blockIdx.y;
    const int b = blockIdx.z & 1, seg = blockIdx.z >> 1;   // seg in [0,3)
    const int q0 = qt * 128;
    const int qw = q0 + wave * 32;

    const int srow = tid >> 2;
    const int sc0  = tid & 3;

    // Q frags (B-operand: rows q=l15): direct global->VGPR, pre-scaled
    short8 qf[2][2];
#pragma unroll
    for (int mi = 0; mi < 2; ++mi)
#pragma unroll
        for (int kk = 0; kk < 2; ++kk)
            qf[mi][kk] = *(const short8*)(Q + (size_t)(b * 2048 + qw + mi * 16 + l15) * 1024
                                            + h * 64 + (quad + 4 * kk) * 8);

    // one packed-mask row per lane per m-tile (q = qw + mj*16 + l15)
    const uint64_t* mrow[2];
#pragma unroll
    for (int mj = 0; mj < 2; ++mj)
        mrow[mj] = mask64 + (size_t)(b * 2048 + qw + mj * 16 + l15) * 32;

    // staging bases
    const uint16_t* Kbase = Kp + (size_t)(b * 2048 + srow) * 1024 + h * 64;
    const uint16_t* Vbase = Vt + (size_t)((b * 16 + h) * 64 + srow) * 2048;

    float4v oaccT[4][2] = {};   // O^T tiles [di][mj]: row=d, col=q
    float2v lsum2[2] = {};

    const int kt_lo = seg * 11;
    const int kt_hi = (seg == 2) ? 32 : kt_lo + 11;

    // preload first tile into regs (T14: issue-early)
    short8 kx0 = *(const short8*)(Kbase + (size_t)(kt_lo * 64) * 1024 + sc0 * 8);
    short8 kx1 = *(const short8*)(Kbase + (size_t)(kt_lo * 64) * 1024 + (sc0 + 4) * 8);
    short8 vx0 = *(const short8*)(Vbase + kt_lo * 64 + sc0 * 8);
    short8 vx1 = *(const short8*)(Vbase + kt_lo * 64 + (sc0 + 4) * 8);

    for (int kt = kt_lo; kt < kt_hi; ++kt) {
        // pre-shift by quad*4: nibble for ni is then a constant-amount shift
        const uint64_t mwq0 = mrow[0][kt] >> (quad * 4);
        const uint64_t mwq1 = mrow[1][kt] >> (quad * 4);
        __syncthreads();
        *(short8*)&sK[srow * VS + sc0 * 8]       = kx0;
        *(short8*)&sK[srow * VS + (sc0 + 4) * 8] = kx1;
        *(short8*)&sV[srow * VS + sc0 * 8]       = vx0;
        *(short8*)&sV[srow * VS + (sc0 + 4) * 8] = vx1;
        __syncthreads();

        // issue NEXT tile's loads now; they complete under this tile's compute
        short8 nk0, nk1, nv0, nv1;
        if (kt + 1 < kt_hi) {
            const int k0n = (kt + 1) * 64;
            nk0 = *(const short8*)(Kbase + (size_t)k0n * 1024 + sc0 * 8);
            nk1 = *(const short8*)(Kbase + (size_t)k0n * 1024 + (sc0 + 4) * 8);
            nv0 = *(const short8*)(Vbase + k0n + sc0 * 8);
            nv1 = *(const short8*)(Vbase + k0n + (sc0 + 4) * 8);
        } else {
            nk0 = kx0; nk1 = kx1; nv0 = vx0; nv1 = vx1;
        }

        // S^T = K @ Q^T : A = K-frag (rows kpos), B = Q-frag (rows q)
        float4v sacc[2][4] = {};
        __builtin_amdgcn_s_setprio(1);
#pragma unroll
        for (int ni = 0; ni < 4; ++ni) {
            const int row = ni * 16 + l15;
#pragma unroll
            for (int kk = 0; kk < 2; ++kk) {
                const short8 kf = *(const short8*)&sK[row * VS + (quad + 4 * kk) * 8];
                sacc[0][ni] = __builtin_amdgcn_mfma_f32_16x16x32_bf16(kf, qf[0][kk], sacc[0][ni], 0, 0, 0);
                sacc[1][ni] = __builtin_amdgcn_mfma_f32_16x16x32_bf16(kf, qf[1][kk], sacc[1][ni], 0, 0, 0);
            }
        }
        __builtin_amdgcn_s_setprio(0);

        // mask + exp2 in place: lane's q = l15 (fixed), kpos = ni*16+quad*4+r.
        // Resulting quartets are exactly 16x16x16 B-frags.
        short4v pf[2][4];
#pragma unroll
        for (int mj = 0; mj < 2; ++mj) {
            const uint64_t mwq = mj ? mwq1 : mwq0;
#pragma unroll
            for (int ni = 0; ni < 4; ++ni) {
                const uint32_t nib = (uint32_t)(mwq >> (ni * 16)) & 0xFu;
                const float p0 = maskexp2(sacc[mj][ni][0], nib, 0);
                const float p1 = maskexp2(sacc[mj][ni][1], nib, 1);
                const float p2 = maskexp2(sacc[mj][ni][2], nib, 2);
                const float p3 = maskexp2(sacc[mj][ni][3], nib, 3);
                float2v lo; lo[0] = p0; lo[1] = p1;
                float2v hi; hi[0] = p2; hi[1] = p3;
                lsum2[mj] += lo;
                lsum2[mj] += hi;
                short4v t;
                t[0] = (short)f2bf_hw(p0);
                t[1] = (short)f2bf_hw(p1);
                t[2] = (short)f2bf_hw(p2);
                t[3] = (short)f2bf_hw(p3);
                pf[mj][ni] = t;
            }
        }

        // O^T += V^T @ P^T : A = Vt-frag (rows d), B = P-frag (rows q)
        __builtin_amdgcn_s_setprio(1);
#pragma unroll
        for (int di = 0; di < 4; ++di) {
            const int row = di * 16 + l15;
#pragma unroll
            for (int ni = 0; ni < 4; ++ni) {
                const short4v vf = *(const short4v*)&sV[row * VS + ni * 16 + quad * 4];
                oaccT[di][0] = mfma16_bf16(vf, pf[0][ni], oaccT[di][0]);
                oaccT[di][1] = mfma16_bf16(vf, pf[1][ni], oaccT[di][1]);
            }
        }
        __builtin_amdgcn_s_setprio(0);

        kx0 = nk0; kx1 = nk1; vx0 = nv0; vx1 = nv1;
    }

#if !__has_builtin(__builtin_amdgcn_mfma_f32_16x16x16bf16_1k)
    asm volatile("s_nop 7\ns_nop 7\ns_nop 7" ::: "memory");   // MFMA->VALU hazard
#endif

    float lsum[2];
#pragma unroll
    for (int mj = 0; mj < 2; ++mj) lsum[mj] = lsum2[mj][0] + lsum2[mj][1];

    // l: sum quads (lanes l15, l15+16, l15+32, l15+48 hold disjoint kpos)
#pragma unroll
    for (int mj = 0; mj < 2; ++mj) {
        lsum[mj] += __shfl_xor(lsum[mj], 16);
        lsum[mj] += __shfl_xor(lsum[mj], 32);
    }

    // store unnormalized partials: O^T lane element (d=di*16+quad*4+r, q=mj*16+l15)
    uint16_t* Op = (seg == 0) ? Oa : (seg == 1) ? Ob : Oc;
#pragma unroll
    for (int mj = 0; mj < 2; ++mj) {
        const int qrow = qw + mj * 16 + l15;
#pragma unroll
        for (int di = 0; di < 4; ++di) {
            short4v o;
#pragma unroll
            for (int r = 0; r < 4; ++r) o[r] = (short)f2bf_hw(oaccT[di][mj][r]);
            *(short4v*)(Op + (size_t)(b * 2048 + qrow) * 1024 + h * 64 + di * 16 + quad * 4) = o;
        }
        if (quad == 0)
            lpart[seg * 65536 + (b * 16 + h) * 2048 + qrow] = lsum[mj];
    }
}

// ---------------------------------------------------------------------------
// combine: Z = (Oa + Ob + Oc) / (la + lb + lc), in-place over Oa's region.
// ---------------------------------------------------------------------------
__global__ __launch_bounds__(256) void combine_kernel(
    const uint16_t* __restrict__ Oa, const uint16_t* __restrict__ Ob,
    const uint16_t* __restrict__ Oc, const float* __restrict__ lpart,
    uint16_t* __restrict__ Z)
{
    const int e8 = blockIdx.x * 256 + threadIdx.x;   // [0, 1M)
    const int flat = e8 * 8;
    const int bh_row = flat >> 10;          // b*2048+row
    const int h = (flat >> 6) & 15;
    const int b = bh_row >> 11;
    const int row = bh_row & 2047;
    const int lidx = (b * 16 + h) * 2048 + row;
    const float inv = 1.0f / fmaxf(lpart[lidx] + lpart[65536 + lidx] + lpart[131072 + lidx], 1e-37f);
    const short8 a = *(const short8*)(Oa + flat);
    const short8 c = *(const short8*)(Ob + flat);
    const short8 d = *(const short8*)(Oc + flat);
    short8 o;
#pragma unroll
    for (int j = 0; j < 8; ++j)
        o[j] = (short)f2bf_sane((bf2f((uint16_t)a[j]) + bf2f((uint16_t)c[j]) + bf2f((uint16_t)d[j])) * inv);
    *(short8*)(Z + flat) = o;
}

// ---------------------------------------------------------------------------
// ws (MB): 0-8 Oa/Zb | 8-16 Vt | 16-24 Ob | 24-25 lpart (over dead cW[wq]) |
// 24-32 cW | 32-33 cB+flag | 33-41 Q | 41-49 K | 49-57 Vb -> Oc | 57-58 mask64
// (cIn is GONE — input conversion fused into qkv staging.)
// ---------------------------------------------------------------------------
extern "C" void kernel_launch(void* const* d_in, const int* in_sizes, int n_in,
                              void* d_out, int out_size, void* d_ws, size_t ws_size,
                              hipStream_t stream)
{
    const void* qx  = d_in[0];
    const void* kx  = d_in[1];
    const void* vx  = d_in[2];
    const int*  msk = (const int*)d_in[3];

    char* ws = (char*)d_ws;
    const size_t MB = 1024 * 1024;
    uint16_t* cW  = (uint16_t*)(ws + 24 * MB);
    uint16_t* cB  = (uint16_t*)(ws + 32 * MB);
    int*      flg = (int*)(ws + 32 * MB + 16 * 1024);
    uint16_t* Qb  = (uint16_t*)(ws + 33 * MB);
    uint16_t* Kb  = (uint16_t*)(ws + 41 * MB);
    uint16_t* Vb  = (uint16_t*)(ws + 49 * MB);
    uint64_t* m64 = (uint64_t*)(ws + 57 * MB);
    uint16_t* Vt  = (uint16_t*)(ws + 8 * MB);
    uint16_t* Oa  = (uint16_t*)(ws);
    uint16_t* Ob  = (uint16_t*)(ws + 16 * MB);
    uint16_t* Oc  = (uint16_t*)(ws + 49 * MB);   // reuse Vb (dead after vtrans)
    float*    lp  = (float*)(ws + 24 * MB);      // reuse cW[wq] (dead after qkv)
    uint16_t* Zb  = Oa;                          // combine writes in place

    pack_kernel<<<1538, 256, 0, stream>>>(
        msk, m64, (const uint16_t*)qx, flg,
        d_in[4], d_in[6], d_in[8], d_in[10],
        d_in[5], d_in[7], d_in[9], d_in[11], cW, cB);
    qkv_kernel<<<dim3(8, 32, 3), 256, 0, stream>>>(
        qx, kx, vx,
        (const uint16_t*)d_in[4], (const uint16_t*)d_in[6], (const uint16_t*)d_in[8],
        (const uint16_t*)d_in[5], (const uint16_t*)d_in[7], (const uint16_t*)d_in[9],
        cW, cB, Qb, Kb, Vb, flg);
    vtrans_kernel<<<dim3(32, 16, 2), 256, 0, stream>>>(Vb, Vt);
    attn_kernel<<<dim3(16, 16, 6), 256, 0, stream>>>(Qb, Kb, Vt, m64, Oa, Ob, Oc, lp);
    combine_kernel<<<4096, 256, 0, stream>>>(Oa, Ob, Oc, lp, Zb);
    out_kernel<<<dim3(8, 64), 256, 0, stream>>>(
        Zb, (const uint16_t*)d_in[10], (const uint16_t*)d_in[11], cW, cB, d_out, flg);
}

// Round 10
// 292.625 us; speedup vs baseline: 1.0683x; 1.0683x over previous
//
#include <hip/hip_runtime.h>
#include <hip/hip_bf16.h>
#include <stdint.h>
#include <math.h>

typedef short short8 __attribute__((ext_vector_type(8)));
typedef short short4v __attribute__((ext_vector_type(4)));
typedef float float4v __attribute__((ext_vector_type(4)));
typedef float float2v __attribute__((ext_vector_type(2)));

static __device__ __forceinline__ float bf2f(uint16_t u) {
    union { uint32_t i; float f; } x; x.i = ((uint32_t)u) << 16; return x.f;
}
static __device__ __forceinline__ uint16_t f2bf(float f) {
    union { float f; uint32_t i; } x; x.f = f;
    uint32_t u = x.i;
    u += 0x7FFFu + ((u >> 16) & 1u);   // RNE
    return (uint16_t)(u >> 16);
}
// hardware f32->bf16 via compiler (RNE, bit-identical to f2bf for finite
// values; lowers to v_cvt_pk_bf16_f32 pairs on gfx950)
static __device__ __forceinline__ uint16_t f2bf_hw(float f) {
    __hip_bfloat16 h = __float2bfloat16(f);
    uint16_t u; __builtin_memcpy(&u, &h, 2); return u;
}
static __device__ __forceinline__ uint16_t f2bf_sane(float f) {
    uint16_t u = f2bf(f);
    if ((u & 0x7F80u) == 0x7F80u) u = 0;
    return u;
}
static __device__ __forceinline__ float san_f32(float f) {
    union { float f; uint32_t i; } x; x.f = f;
    if (((x.i >> 23) & 0xFFu) == 0xFFu) return 0.f;
    return x.f;
}
static __device__ __forceinline__ void gll16(const void* g, void* l) {
    __builtin_amdgcn_global_load_lds((const __attribute__((address_space(1))) void*)g,
                                     (__attribute__((address_space(3))) void*)l,
                                     16, 0, 0);
}
static __device__ __forceinline__ short8 load8(const void* p, size_t off, int fp32) {
    if (!fp32) return *(const short8*)((const uint16_t*)p + off);
    const float* f = (const float*)p + off;
    const float4v a = *(const float4v*)f;
    const float4v b = *(const float4v*)(f + 4);
    short8 r;
    r[0] = (short)f2bf(a[0]); r[1] = (short)f2bf(a[1]);
    r[2] = (short)f2bf(a[2]); r[3] = (short)f2bf(a[3]);
    r[4] = (short)f2bf(b[0]); r[5] = (short)f2bf(b[1]);
    r[6] = (short)f2bf(b[2]); r[7] = (short)f2bf(b[3]);
    return r;
}

// raw 2^x (hardware v_exp_f32). Q is pre-scaled by log2(e)/sqrt(DK).
static __device__ __forceinline__ float fexp2(float x) {
#if __has_builtin(__builtin_amdgcn_exp2f)
    return __builtin_amdgcn_exp2f(x);
#else
    float r; asm("v_exp_f32 %0, %1\ns_nop 0" : "=v"(r) : "v"(x)); return r;
#endif
}

// masked exp2: bit r of nib selects s, else -inf (exp2(-inf)=+0).
static __device__ __forceinline__ float maskexp2(float s, uint32_t nib, int r) {
    union { float f; uint32_t u; } x; x.f = s;
    const uint32_t keep = (uint32_t)(((int32_t)(nib << (31 - r))) >> 31);
    x.u = (x.u & keep) | (~keep & 0xFF800000u);
    return fexp2(x.f);
}

// 16x16x16 bf16 MFMA: builtin if present, else raw asm (hazard nops at use site)
static __device__ __forceinline__ float4v mfma16_bf16(short4v a, short4v b, float4v c) {
#if __has_builtin(__builtin_amdgcn_mfma_f32_16x16x16bf16_1k)
    return __builtin_amdgcn_mfma_f32_16x16x16bf16_1k(a, b, c, 0, 0, 0);
#else
    float4v d = c;
    asm volatile("v_mfma_f32_16x16x16_bf16 %0, %1, %2, %0"
                 : "+v"(d) : "v"(a), "v"(b));
    return d;
#endif
}

// ---------------------------------------------------------------------------
// pack: blocks 0-1023: mask bitpack int32[4096][2048] -> uint64[4096][32].
// block 1024: dtype probe -> *flag. blocks 1025-1536: weight fp32->bf16
// convert (mode decided locally — deterministic, no race). block 1537: bias.
// ---------------------------------------------------------------------------
__global__ __launch_bounds__(256) void pack_kernel(
    const int* __restrict__ mask, uint64_t* __restrict__ mask64,
    const uint16_t* __restrict__ qx, int* __restrict__ flag,
    const void* wq, const void* wk, const void* wv, const void* wo,
    const void* bq, const void* bk, const void* bv, const void* bo,
    uint16_t* __restrict__ cW, uint16_t* __restrict__ cB)
{
    const int bx = blockIdx.x;
    const int tid = threadIdx.x;
    if (bx < 1024) {
        const int wave = tid >> 6, lane = tid & 63;
        const int row = bx * 4 + wave;
        const int* src = mask + (size_t)row * 2048;
#pragma unroll 4
        for (int j = 0; j < 32; ++j) {
            const int m = src[j * 64 + lane];
            const uint64_t bal = __ballot(m != 0);
            if (lane == 0) mask64[(size_t)row * 32 + j] = bal;
        }
        return;
    }
    // local dtype probe (blocks >= 1024): scan first 16K halfwords of qx
    __shared__ int s;
    if (tid == 0) s = 0;
    __syncthreads();
    int bad = 0;
#pragma unroll 8
    for (int i = 0; i < 64; ++i) {
        const uint16_t u = qx[tid * 64 + i];
        bad |= ((u & 0x7F80u) == 0x7F80u) ? 1 : 0;
    }
    if (bad) atomicOr(&s, 1);
    __syncthreads();
    const int mode = s;
    if (bx == 1024) {
        if (tid == 0) *flag = mode;
        return;
    }
    if (!mode) return;
    if (bx < 1537) {
        const int idx8 = (bx - 1025) * 256 + tid;    // [0, 131072)
#pragma unroll
        for (int t = 0; t < 4; ++t) {
            const void* src = (t == 0) ? wq : (t == 1) ? wk : (t == 2) ? wv : wo;
            *(short8*)(cW + (size_t)t * 1048576 + (size_t)idx8 * 8) =
                load8(src, (size_t)idx8 * 8, 1);
        }
    } else {
        if (tid < 128) {
#pragma unroll
            for (int t = 0; t < 4; ++t) {
                const void* src = (t == 0) ? bq : (t == 1) ? bk : (t == 2) ? bv : bo;
                *(short8*)(cB + t * 1024 + tid * 8) = load8(src, (size_t)tid * 8, 1);
            }
        }
    }
}

// ---------------------------------------------------------------------------
// m97-style GEMM: C = A @ W^T + bias, all-bf16 compute, fp32 acc.
// afp32=1: A fp32 in global, staged via T14 PIPELINE — fp32 loads for tile
// k+1 issue right after barrier2 and fly under tile k's MFMA compute; the
// converted ds_write happens at the next iteration's top. r9's synchronous
// version exposed full load latency per k-step (qkv 81us, MfmaUtil 12%).
// W always bf16 via gll16. (bx, by) passed in for XCD remap (T1).
// ---------------------------------------------------------------------------
template <int MI, int NI>
static __device__ __forceinline__ void gemm_tile(
    const void* __restrict__ A, int afp32,
    const uint16_t* __restrict__ W,
    const uint16_t* __restrict__ bias, void* __restrict__ C,
    int c_fp32, float out_scale, int bx, int by)
{
    constexpr int TM = MI * 32, TN = NI * 32;
    constexpr int GA = (TM / 16) / 4;     // A-staging groups per wave
    __shared__ __align__(16) uint16_t sA[TM * 32];
    __shared__ __align__(16) uint16_t sB[TN * 32];

    const int tid  = threadIdx.x;
    const int wave = tid >> 6;
    const int lane = tid & 63;
    const int quad = lane >> 4;
    const int l15  = lane & 15;
    const int m0 = by * TM;
    const int n0 = bx * TN;
    const int wm = (wave >> 1) * (MI * 16);
    const int wn = (wave & 1) * (NI * 16);
    const int r16 = lane >> 2;
    const int ch  = lane & 3;

    float4v acc[MI][NI] = {};
    float4v pa[GA][2];
    const float* Af = (const float*)A;

    if (afp32) {
#pragma unroll
        for (int gi = 0; gi < GA; ++gi) {
            const int g = wave + gi * 4;
            const float* p = Af + (size_t)(m0 + g * 16 + r16) * 1024 + ch * 8;
            pa[gi][0] = *(const float4v*)p;
            pa[gi][1] = *(const float4v*)(p + 4);
        }
    }

    for (int k0 = 0; k0 < 1024; k0 += 32) {
        __syncthreads();
        if (afp32) {
#pragma unroll
            for (int gi = 0; gi < GA; ++gi) {
                const int g = wave + gi * 4;
                short8 r;
                r[0] = (short)f2bf_hw(pa[gi][0][0]);
                r[1] = (short)f2bf_hw(pa[gi][0][1]);
                r[2] = (short)f2bf_hw(pa[gi][0][2]);
                r[3] = (short)f2bf_hw(pa[gi][0][3]);
                r[4] = (short)f2bf_hw(pa[gi][1][0]);
                r[5] = (short)f2bf_hw(pa[gi][1][1]);
                r[6] = (short)f2bf_hw(pa[gi][1][2]);
                r[7] = (short)f2bf_hw(pa[gi][1][3]);
                *(short8*)((char*)sA + (size_t)g * 1024 + (size_t)lane * 16) = r;
            }
        } else {
            const uint16_t* Ah = (const uint16_t*)A;
#pragma unroll
            for (int g = wave; g < TM / 16; g += 4)
                gll16(Ah + (size_t)(m0 + g * 16 + r16) * 1024 + k0 + ch * 8,
                      (char*)sA + (size_t)g * 1024);
        }
#pragma unroll
        for (int g = wave; g < TN / 16; g += 4)
            gll16(W + (size_t)(n0 + g * 16 + r16) * 1024 + k0 + ch * 8,
                  (char*)sB + (size_t)g * 1024);
        asm volatile("s_waitcnt vmcnt(0)" ::: "memory");
        __syncthreads();

        // T14: issue NEXT k-step's fp32 A loads now; they complete under MFMA
        if (afp32 && k0 + 32 < 1024) {
#pragma unroll
            for (int gi = 0; gi < GA; ++gi) {
                const int g = wave + gi * 4;
                const float* p = Af + (size_t)(m0 + g * 16 + r16) * 1024 + (k0 + 32) + ch * 8;
                pa[gi][0] = *(const float4v*)p;
                pa[gi][1] = *(const float4v*)(p + 4);
            }
        }

        short8 af[MI], bfr[NI];
#pragma unroll
        for (int i = 0; i < MI; ++i)
            af[i] = *(const short8*)&sA[(wm + i * 16 + l15) * 32 + quad * 8];
#pragma unroll
        for (int j = 0; j < NI; ++j)
            bfr[j] = *(const short8*)&sB[(wn + j * 16 + l15) * 32 + quad * 8];
#pragma unroll
        for (int mi = 0; mi < MI; ++mi)
#pragma unroll
            for (int ni = 0; ni < NI; ++ni)
                acc[mi][ni] = __builtin_amdgcn_mfma_f32_16x16x32_bf16(
                    af[mi], bfr[ni], acc[mi][ni], 0, 0, 0);
    }

#pragma unroll
    for (int ni = 0; ni < NI; ++ni) {
        const int n = n0 + wn + ni * 16 + l15;
        const float bv = bf2f(bias[n]);
#pragma unroll
        for (int mi = 0; mi < MI; ++mi) {
            const int mbase = m0 + wm + mi * 16 + quad * 4;
#pragma unroll
            for (int r = 0; r < 4; ++r) {
                const float v = (acc[mi][ni][r] + bv) * out_scale;
                const size_t idx = (size_t)(mbase + r) * 1024 + n;
                if (c_fp32) ((float*)C)[idx] = san_f32(v);
                else        ((uint16_t*)C)[idx] = f2bf_sane(v);
            }
        }
    }
}

// XCD-affinity remap (T1): all 8 N-tile blocks of one (z, M-panel) share
// wgid%8 -> same XCD -> A-panel read once per XCD.
__global__ __launch_bounds__(256) void qkv_kernel(
    const void* qxr, const void* kxr, const void* vxr,
    const uint16_t* rwq, const uint16_t* rwk, const uint16_t* rwv,
    const uint16_t* rbq, const uint16_t* rbk, const uint16_t* rbv,
    const uint16_t* cW, const uint16_t* cB,
    uint16_t* Q, uint16_t* K, uint16_t* V, const int* flag)
{
    const int mode = *flag;
    const int wgid = blockIdx.x + (blockIdx.y << 3) + (blockIdx.z << 8);
    const int xcd = wgid & 7;
    const int s   = wgid >> 3;             // [0,96)
    const int panel = xcd * 12 + (s >> 3); // [0,96)
    const int bx = s & 7;
    const int z  = panel >> 5;             // [0,3)
    const int by = panel & 31;

    const void* A = (z == 0) ? qxr : (z == 1) ? kxr : vxr;  // fp32 if mode
    const uint16_t* W = mode ? cW + (size_t)z * 1048576
                             : ((z == 0) ? rwq : (z == 1) ? rwk : rwv);
    const uint16_t* b = mode ? cB + z * 1024
                             : ((z == 0) ? rbq : (z == 1) ? rbk : rbv);
    uint16_t* C = (z == 0) ? Q : (z == 1) ? K : V;
    // fold log2(e)/sqrt(DK) into Q so attention uses raw v_exp_f32 (2^x)
    const float sc = (z == 0) ? 0.18033688f : 1.0f;
    gemm_tile<4, 4>(A, mode, W, b, C, 0, sc, bx, by);
}

__global__ __launch_bounds__(256) void out_kernel(
    const uint16_t* Z, const uint16_t* rwo, const uint16_t* rbo,
    const uint16_t* cW, const uint16_t* cB, void* out, const int* flag)
{
    const int mode = *flag;
    const uint16_t* W = mode ? cW + 3 * 1048576 : rwo;
    const uint16_t* b = mode ? cB + 3 * 1024 : rbo;
    const int wgid = blockIdx.x + (blockIdx.y << 3);
    const int xcd = wgid & 7;
    const int s   = wgid >> 3;            // [0,64)
    const int by  = xcd * 8 + (s >> 3);   // [0,64)
    const int bx  = s & 7;
    gemm_tile<2, 4>(Z, 0, W, b, out, mode, 1.0f, bx, by);
}

// ---------------------------------------------------------------------------
// V transpose: V[B*L][H*64] -> Vt[B][H][64][L]  (coalesced both sides)
// ---------------------------------------------------------------------------
__global__ __launch_bounds__(256) void vtrans_kernel(
    const uint16_t* __restrict__ Vp, uint16_t* __restrict__ Vt)
{
    __shared__ __align__(16) uint16_t t[64][72];
    const int tid = threadIdx.x;
    const int lt = blockIdx.x, h = blockIdx.y, b = blockIdx.z;
#pragma unroll
    for (int p = 0; p < 2; ++p) {
        const int r = p * 32 + (tid >> 3);
        const int c = (tid & 7) * 8;
        *(short8*)&t[r][c] =
            *(const short8*)(Vp + (size_t)(b * 2048 + lt * 64 + r) * 1024 + h * 64 + c);
    }
    __syncthreads();
#pragma unroll
    for (int p = 0; p < 2; ++p) {
        const int d = p * 32 + (tid >> 3);
        const int c = (tid & 7) * 8;
        short8 v;
#pragma unroll
        for (int j = 0; j < 8; ++j) v[j] = (short)t[c + j][d];
        *(short8*)(Vt + (size_t)((b * 16 + h) * 64 + d) * 2048 + lt * 64 + c) = v;
    }
}

// ---------------------------------------------------------------------------
// Flash attention v12 (unchanged): kt-split x3, T14 reg prefetch, setprio,
// exp2-prescale, bfi mask, f2bf_hw packs.
// ---------------------------------------------------------------------------
#define VS 72

__global__ __launch_bounds__(256, 4) void attn_kernel(
    const uint16_t* __restrict__ Q, const uint16_t* __restrict__ Kp,
    const uint16_t* __restrict__ Vt, const uint64_t* __restrict__ mask64,
    uint16_t* __restrict__ Oa, uint16_t* __restrict__ Ob,
    uint16_t* __restrict__ Oc, float* __restrict__ lpart)
{
    __shared__ __align__(16) uint16_t sK[64 * VS];
    __shared__ __align__(16) uint16_t sV[64 * VS];

    const int tid = threadIdx.x;
    const int wave = tid >> 6, lane = tid & 63;
    const int quad = lane >> 4, l15 = lane & 15;
    const int qt = blockIdx.x, h = blockIdx.y;
    const int b = blockIdx.z & 1, seg = blockIdx.z >> 1;   // seg in [0,3)
    const int q0 = qt * 128;
    const int qw = q0 + wave * 32;

    const int srow = tid >> 2;
    const int sc0  = tid & 3;

    // Q frags (B-operand: rows q=l15): direct global->VGPR, pre-scaled
    short8 qf[2][2];
#pragma unroll
    for (int mi = 0; mi < 2; ++mi)
#pragma unroll
        for (int kk = 0; kk < 2; ++kk)
            qf[mi][kk] = *(const short8*)(Q + (size_t)(b * 2048 + qw + mi * 16 + l15) * 1024
                                            + h * 64 + (quad + 4 * kk) * 8);

    // one packed-mask row per lane per m-tile (q = qw + mj*16 + l15)
    const uint64_t* mrow[2];
#pragma unroll
    for (int mj = 0; mj < 2; ++mj)
        mrow[mj] = mask64 + (size_t)(b * 2048 + qw + mj * 16 + l15) * 32;

    // staging bases
    const uint16_t* Kbase = Kp + (size_t)(b * 2048 + srow) * 1024 + h * 64;
    const uint16_t* Vbase = Vt + (size_t)((b * 16 + h) * 64 + srow) * 2048;

    float4v oaccT[4][2] = {};   // O^T tiles [di][mj]: row=d, col=q
    float2v lsum2[2] = {};

    const int kt_lo = seg * 11;
    const int kt_hi = (seg == 2) ? 32 : kt_lo + 11;

    // preload first tile into regs (T14: issue-early)
    short8 kx0 = *(const short8*)(Kbase + (size_t)(kt_lo * 64) * 1024 + sc0 * 8);
    short8 kx1 = *(const short8*)(Kbase + (size_t)(kt_lo * 64) * 1024 + (sc0 + 4) * 8);
    short8 vx0 = *(const short8*)(Vbase + kt_lo * 64 + sc0 * 8);
    short8 vx1 = *(const short8*)(Vbase + kt_lo * 64 + (sc0 + 4) * 8);

    for (int kt = kt_lo; kt < kt_hi; ++kt) {
        // pre-shift by quad*4: nibble for ni is then a constant-amount shift
        const uint64_t mwq0 = mrow[0][kt] >> (quad * 4);
        const uint64_t mwq1 = mrow[1][kt] >> (quad * 4);
        __syncthreads();
        *(short8*)&sK[srow * VS + sc0 * 8]       = kx0;
        *(short8*)&sK[srow * VS + (sc0 + 4) * 8] = kx1;
        *(short8*)&sV[srow * VS + sc0 * 8]       = vx0;
        *(short8*)&sV[srow * VS + (sc0 + 4) * 8] = vx1;
        __syncthreads();

        // issue NEXT tile's loads now; they complete under this tile's compute
        short8 nk0, nk1, nv0, nv1;
        if (kt + 1 < kt_hi) {
            const int k0n = (kt + 1) * 64;
            nk0 = *(const short8*)(Kbase + (size_t)k0n * 1024 + sc0 * 8);
            nk1 = *(const short8*)(Kbase + (size_t)k0n * 1024 + (sc0 + 4) * 8);
            nv0 = *(const short8*)(Vbase + k0n + sc0 * 8);
            nv1 = *(const short8*)(Vbase + k0n + (sc0 + 4) * 8);
        } else {
            nk0 = kx0; nk1 = kx1; nv0 = vx0; nv1 = vx1;
        }

        // S^T = K @ Q^T : A = K-frag (rows kpos), B = Q-frag (rows q)
        float4v sacc[2][4] = {};
        __builtin_amdgcn_s_setprio(1);
#pragma unroll
        for (int ni = 0; ni < 4; ++ni) {
            const int row = ni * 16 + l15;
#pragma unroll
            for (int kk = 0; kk < 2; ++kk) {
                const short8 kf = *(const short8*)&sK[row * VS + (quad + 4 * kk) * 8];
                sacc[0][ni] = __builtin_amdgcn_mfma_f32_16x16x32_bf16(kf, qf[0][kk], sacc[0][ni], 0, 0, 0);
                sacc[1][ni] = __builtin_amdgcn_mfma_f32_16x16x32_bf16(kf, qf[1][kk], sacc[1][ni], 0, 0, 0);
            }
        }
        __builtin_amdgcn_s_setprio(0);

        // mask + exp2 in place: lane's q = l15 (fixed), kpos = ni*16+quad*4+r.
        // Resulting quartets are exactly 16x16x16 B-frags.
        short4v pf[2][4];
#pragma unroll
        for (int mj = 0; mj < 2; ++mj) {
            const uint64_t mwq = mj ? mwq1 : mwq0;
#pragma unroll
            for (int ni = 0; ni < 4; ++ni) {
                const uint32_t nib = (uint32_t)(mwq >> (ni * 16)) & 0xFu;
                const float p0 = maskexp2(sacc[mj][ni][0], nib, 0);
                const float p1 = maskexp2(sacc[mj][ni][1], nib, 1);
                const float p2 = maskexp2(sacc[mj][ni][2], nib, 2);
                const float p3 = maskexp2(sacc[mj][ni][3], nib, 3);
                float2v lo; lo[0] = p0; lo[1] = p1;
                float2v hi; hi[0] = p2; hi[1] = p3;
                lsum2[mj] += lo;
                lsum2[mj] += hi;
                short4v t;
                t[0] = (short)f2bf_hw(p0);
                t[1] = (short)f2bf_hw(p1);
                t[2] = (short)f2bf_hw(p2);
                t[3] = (short)f2bf_hw(p3);
                pf[mj][ni] = t;
            }
        }

        // O^T += V^T @ P^T : A = Vt-frag (rows d), B = P-frag (rows q)
        __builtin_amdgcn_s_setprio(1);
#pragma unroll
        for (int di = 0; di < 4; ++di) {
            const int row = di * 16 + l15;
#pragma unroll
            for (int ni = 0; ni < 4; ++ni) {
                const short4v vf = *(const short4v*)&sV[row * VS + ni * 16 + quad * 4];
                oaccT[di][0] = mfma16_bf16(vf, pf[0][ni], oaccT[di][0]);
                oaccT[di][1] = mfma16_bf16(vf, pf[1][ni], oaccT[di][1]);
            }
        }
        __builtin_amdgcn_s_setprio(0);

        kx0 = nk0; kx1 = nk1; vx0 = nv0; vx1 = nv1;
    }

#if !__has_builtin(__builtin_amdgcn_mfma_f32_16x16x16bf16_1k)
    asm volatile("s_nop 7\ns_nop 7\ns_nop 7" ::: "memory");   // MFMA->VALU hazard
#endif

    float lsum[2];
#pragma unroll
    for (int mj = 0; mj < 2; ++mj) lsum[mj] = lsum2[mj][0] + lsum2[mj][1];

    // l: sum quads (lanes l15, l15+16, l15+32, l15+48 hold disjoint kpos)
#pragma unroll
    for (int mj = 0; mj < 2; ++mj) {
        lsum[mj] += __shfl_xor(lsum[mj], 16);
        lsum[mj] += __shfl_xor(lsum[mj], 32);
    }

    // store unnormalized partials: O^T lane element (d=di*16+quad*4+r, q=mj*16+l15)
    uint16_t* Op = (seg == 0) ? Oa : (seg == 1) ? Ob : Oc;
#pragma unroll
    for (int mj = 0; mj < 2; ++mj) {
        const int qrow = qw + mj * 16 + l15;
#pragma unroll
        for (int di = 0; di < 4; ++di) {
            short4v o;
#pragma unroll
            for (int r = 0; r < 4; ++r) o[r] = (short)f2bf_hw(oaccT[di][mj][r]);
            *(short4v*)(Op + (size_t)(b * 2048 + qrow) * 1024 + h * 64 + di * 16 + quad * 4) = o;
        }
        if (quad == 0)
            lpart[seg * 65536 + (b * 16 + h) * 2048 + qrow] = lsum[mj];
    }
}

// ---------------------------------------------------------------------------
// combine: Z = (Oa + Ob + Oc) / (la + lb + lc), in-place over Oa's region.
// ---------------------------------------------------------------------------
__global__ __launch_bounds__(256) void combine_kernel(
    const uint16_t* __restrict__ Oa, const uint16_t* __restrict__ Ob,
    const uint16_t* __restrict__ Oc, const float* __restrict__ lpart,
    uint16_t* __restrict__ Z)
{
    const int e8 = blockIdx.x * 256 + threadIdx.x;   // [0, 1M)
    const int flat = e8 * 8;
    const int bh_row = flat >> 10;          // b*2048+row
    const int h = (flat >> 6) & 15;
    const int b = bh_row >> 11;
    const int row = bh_row & 2047;
    const int lidx = (b * 16 + h) * 2048 + row;
    const float inv = 1.0f / fmaxf(lpart[lidx] + lpart[65536 + lidx] + lpart[131072 + lidx], 1e-37f);
    const short8 a = *(const short8*)(Oa + flat);
    const short8 c = *(const short8*)(Ob + flat);
    const short8 d = *(const short8*)(Oc + flat);
    short8 o;
#pragma unroll
    for (int j = 0; j < 8; ++j)
        o[j] = (short)f2bf_sane((bf2f((uint16_t)a[j]) + bf2f((uint16_t)c[j]) + bf2f((uint16_t)d[j])) * inv);
    *(short8*)(Z + flat) = o;
}

// ---------------------------------------------------------------------------
// ws (MB): 0-8 Oa/Zb | 8-16 Vt | 16-24 Ob | 24-25 lpart (over dead cW[wq]) |
// 24-32 cW | 32-33 cB+flag | 33-41 Q | 41-49 K | 49-57 Vb -> Oc | 57-58 mask64
// ---------------------------------------------------------------------------
extern "C" void kernel_launch(void* const* d_in, const int* in_sizes, int n_in,
                              void* d_out, int out_size, void* d_ws, size_t ws_size,
                              hipStream_t stream)
{
    const void* qx  = d_in[0];
    const void* kx  = d_in[1];
    const void* vx  = d_in[2];
    const int*  msk = (const int*)d_in[3];

    char* ws = (char*)d_ws;
    const size_t MB = 1024 * 1024;
    uint16_t* cW  = (uint16_t*)(ws + 24 * MB);
    uint16_t* cB  = (uint16_t*)(ws + 32 * MB);
    int*      flg = (int*)(ws + 32 * MB + 16 * 1024);
    uint16_t* Qb  = (uint16_t*)(ws + 33 * MB);
    uint16_t* Kb  = (uint16_t*)(ws + 41 * MB);
    uint16_t* Vb  = (uint16_t*)(ws + 49 * MB);
    uint64_t* m64 = (uint64_t*)(ws + 57 * MB);
    uint16_t* Vt  = (uint16_t*)(ws + 8 * MB);
    uint16_t* Oa  = (uint16_t*)(ws);
    uint16_t* Ob  = (uint16_t*)(ws + 16 * MB);
    uint16_t* Oc  = (uint16_t*)(ws + 49 * MB);   // reuse Vb (dead after vtrans)
    float*    lp  = (float*)(ws + 24 * MB);      // reuse cW[wq] (dead after qkv)
    uint16_t* Zb  = Oa;                          // combine writes in place

    pack_kernel<<<1538, 256, 0, stream>>>(
        msk, m64, (const uint16_t*)qx, flg,
        d_in[4], d_in[6], d_in[8], d_in[10],
        d_in[5], d_in[7], d_in[9], d_in[11], cW, cB);
    qkv_kernel<<<dim3(8, 32, 3), 256, 0, stream>>>(
        qx, kx, vx,
        (const uint16_t*)d_in[4], (const uint16_t*)d_in[6], (const uint16_t*)d_in[8],
        (const uint16_t*)d_in[5], (const uint16_t*)d_in[7], (const uint16_t*)d_in[9],
        cW, cB, Qb, Kb, Vb, flg);
    vtrans_kernel<<<dim3(32, 16, 2), 256, 0, stream>>>(Vb, Vt);
    attn_kernel<<<dim3(16, 16, 6), 256, 0, stream>>>(Qb, Kb, Vt, m64, Oa, Ob, Oc, lp);
    combine_kernel<<<4096, 256, 0, stream>>>(Oa, Ob, Oc, lp, Zb);
    out_kernel<<<dim3(8, 64), 256, 0, stream>>>(
        Zb, (const uint16_t*)d_in[10], (const uint16_t*)d_in[11], cW, cB, d_out, flg);
}